// Round 2
// baseline (762.499 us; speedup 1.0000x reference)
//
#include <hip/hip_runtime.h>
#include <hip/hip_bf16.h>

// GNN message passing: gather(x[src],x[tgt],ef) -> MLP(112->128->128->48) -> scatter-mean.
// R10 = R9 + L2 weights hoisted to per-thread REGISTERS (32 short8 frags = 128 VGPR,
// loaded once from global wt2 before the tile loop). Post-mortem of R9 showed the tile
// is LDS-throughput-bound: 800 ds_read_b128/tile/CU (~9.6k cyc of the 21.8k tile), and
// 608KB of the 800KB/tile LDS reads are the 8 waves EACH re-reading all weight
// matrices every tile. L2-in-regs removes 256 of those reads/tile (-3.1k cyc) and the
// 32KB lw2 buffer (LDS 145->113KB). No remap, no new barriers; L1/L3 stay in LDS
// (adding them would exceed the 256-VGPR cap at 2 waves/SIMD).
// R9 kept: software-pipelined gather (srt 2 ahead, 14xfloat4 1 ahead in regs),
// vmcnt-preserving raw barriers (lgkmcnt(0)+s_barrier), setprio(1) around MFMA,
// interior-segment plain stores in the reduce.
// R7 lesson kept: stay under the VGPR spill cliff; barriers keep LDS liveness short.

#define NN 100000
#define NE 1600000
#define NF 48
#define TOT 112
#define HID 128
#define TILE 256
#define NTILE 6250  // NE/256

typedef __attribute__((ext_vector_type(8))) short short8;
typedef __attribute__((ext_vector_type(4))) float floatx4;

__device__ __forceinline__ unsigned short f2bf(float f) {
    union { float f; unsigned u; } v; v.f = f;
    unsigned u = v.u;
    return (unsigned short)((u + 0x7FFFu + ((u >> 16) & 1u)) >> 16);  // RNE
}
__device__ __forceinline__ unsigned pk2(float a, float b) {
    __hip_bfloat162 h = __float22bfloat162_rn(make_float2(a, b));
    return *(unsigned*)&h;  // low16 = a, high16 = b
}

// Raw barrier: drain own LDS ops, sync waves, but do NOT drain vmcnt --
// keeps the next-tile gather prefetch in flight across the barrier.
__device__ __forceinline__ void bar_lgkm() {
    asm volatile("s_waitcnt lgkmcnt(0)" ::: "memory");
    __builtin_amdgcn_s_barrier();
}

// ---- hist (blocks 0..6249) + prep W->WT bf16 (blocks 6250..6401)
__global__ void hist_prep_kernel(const int* __restrict__ ei, int* __restrict__ cnt,
                                 const float* __restrict__ W1, const float* __restrict__ W2,
                                 const float* __restrict__ W3,
                                 unsigned short* __restrict__ wt1,
                                 unsigned short* __restrict__ wt2,
                                 unsigned short* __restrict__ wt3) {
    if (blockIdx.x < NTILE) {
        int e = blockIdx.x * 256 + threadIdx.x;  // NE exact
        atomicAdd(cnt + ei[NE + e], 1);
        return;
    }
    int idx = (blockIdx.x - NTILE) * 256 + threadIdx.x;
    if (idx < 16384) {
        int n = idx >> 7, k = idx & 127;
        wt1[idx] = (k < TOT) ? f2bf(W1[k * HID + n]) : (unsigned short)0;
    } else if (idx < 32768) {
        int j = idx - 16384; int n = j >> 7, k = j & 127;
        wt2[j] = f2bf(W2[k * HID + n]);
    } else if (idx < 38912) {
        int j = idx - 32768; int n = j >> 7, k = j & 127;
        wt3[j] = f2bf(W3[k * NF + n]);
    }
}

// pure block scan + one atomic/block -> exclusive offsets
__global__ void scan_kernel(const int* __restrict__ cnt, int* __restrict__ off,
                            int* __restrict__ counter) {
    __shared__ int sd[256];
    __shared__ int sbase;
    int tid = threadIdx.x;
    int n = blockIdx.x * 256 + tid;
    int v = (n < NN) ? cnt[n] : 0;
    sd[tid] = v;
    __syncthreads();
#pragma unroll
    for (int d = 1; d < 256; d <<= 1) {
        int t = (tid >= d) ? sd[tid - d] : 0;
        __syncthreads();
        sd[tid] += t;
        __syncthreads();
    }
    if (tid == 255) sbase = atomicAdd(counter, sd[255]);
    __syncthreads();
    if (n < NN) off[n] = sbase + sd[tid] - v;  // exclusive
}

__global__ void place_kernel(const int* __restrict__ ei, int* __restrict__ off,
                             unsigned long long* __restrict__ srt) {
    int e = blockIdx.x * 256 + threadIdx.x;  // NE exact
    int t = ei[NE + e];
    int p = atomicAdd(off + t, 1);  // off consumed (dead after this kernel)
    srt[p] = (unsigned long long)e | ((unsigned long long)ei[e] << 21) |
             ((unsigned long long)t << 38);
}

// swizzled LDS frag helper: row stride 256B, 16B granules, granule g stored at g^(row&15)
__device__ __forceinline__ const short8* frag_ptr(const unsigned short* base, int row, int s,
                                                  int lane15, int quad) {
    return (const short8*)((const char*)base + row * 256 + (((s * 4 + quad) ^ lane15) << 4));
}

// issue 14 float4 gather loads for half an edge row (sub = which half)
__device__ __forceinline__ void gather_issue(const float* __restrict__ x,
                                             const float* __restrict__ ef,
                                             unsigned long long pk, int sub, float4* v) {
    int eid = (int)(pk & 0x1FFFFFull);
    int src = (int)((pk >> 21) & 0x1FFFFull);
    int tgt = (int)(pk >> 38);
#pragma unroll
    for (int j = 0; j < 14; ++j) {
        int p = 2 * j + sub;
        const float4* gp;
        if (p < 12)      gp = (const float4*)(x + 48 * (size_t)src) + p;
        else if (p < 24) gp = (const float4*)(x + 48 * (size_t)tgt) + (p - 12);
        else             gp = (const float4*)(ef + 16 * (size_t)eid) + (p - 24);
        v[j] = *gp;
    }
}

__launch_bounds__(512, 2)
__global__ void gemm_kernel(const float* __restrict__ x, const float* __restrict__ ef,
                            const unsigned long long* __restrict__ srt,
                            const unsigned short* __restrict__ wt1,
                            const unsigned short* __restrict__ wt2,
                            const unsigned short* __restrict__ wt3,
                            const float* __restrict__ b1, const float* __restrict__ b2,
                            float* __restrict__ out_acc) {
    __shared__ __align__(16) unsigned short lw1[128 * 128];  // 32 KB
    __shared__ __align__(16) unsigned short lw3[48 * 128];   // 12 KB
    __shared__ __align__(16) unsigned short ea[TILE * 128];  // 64 KB: E -> h1 -> h2 -> msg
    __shared__ float lb1[128], lb2[128];
    __shared__ int ltgt[TILE];
    __shared__ int seg_start[TILE + 4];
    __shared__ int seg_tgt[TILE];
    __shared__ int nseg;

    const int tid = threadIdx.x;
    // ---- stage L1/L3 weights swizzled (once per persistent block); L2 goes to regs
    const uint4* s1 = (const uint4*)wt1;
    for (int i = tid; i < 2048; i += 512) {
        int n = i >> 4, g = i & 15;
        *(uint4*)((char*)lw1 + n * 256 + ((g ^ (n & 15)) << 4)) = s1[i];
    }
    const uint4* s3 = (const uint4*)wt3;
    for (int i = tid; i < 768; i += 512) {
        int n = i >> 4, g = i & 15;
        *(uint4*)((char*)lw3 + n * 256 + ((g ^ (n & 15)) << 4)) = s3[i];
    }
    if (tid < 128) lb1[tid] = b1[tid];
    else if (tid < 256) lb2[tid - 128] = b2[tid - 128];
    __syncthreads();

    const int l15 = tid & 15;
    const int q = (tid & 63) >> 4;
    const int ln = tid & 63;
    const int wave = tid >> 6;
    const int sub = ln & 1;                  // 2 lanes per edge row
    const int grow = wave * 32 + (ln >> 1);  // tile-local edge row (0..255)
    const int gl15 = grow & 15;
    const int G = gridDim.x;

    // ---- L2 weight frags resident in registers for the whole kernel (128 VGPR).
    // frag (mt,s) = unswizzled granule g=s*4+q of row mt*16+l15 (see frag_ptr identity:
    // stored granule g^(row&15) read back at (s*4+q)^l15 with row&15==l15 -> g=s*4+q).
    short8 w2r[8][4];
#pragma unroll
    for (int mt = 0; mt < 8; ++mt)
#pragma unroll
        for (int s = 0; s < 4; ++s)
            w2r[mt][s] = *(const short8*)(wt2 + (mt * 16 + l15) * 128 + (s * 4 + q) * 8);

    // ---- pipeline prologue: srt 2 ahead, gather data 1 ahead (held in registers)
    unsigned long long pkCur = srt[(size_t)blockIdx.x * TILE + grow];
    unsigned long long pkNext = (blockIdx.x + G < NTILE)
        ? srt[(size_t)(blockIdx.x + G) * TILE + grow] : 0ull;
    float4 v[14];
    gather_issue(x, ef, pkCur, sub, v);

    for (int tile = blockIdx.x; tile < NTILE; tile += G) {
        // ---- consume prefetched gather: convert + swizzled store into ea (own rows only)
        {
            int tgt = (int)(pkCur >> 38);
            if (sub == 0) ltgt[grow] = tgt;
#pragma unroll
            for (int j = 0; j < 14; ++j) {
                uint2 h = make_uint2(pk2(v[j].x, v[j].y), pk2(v[j].z, v[j].w));
                *(uint2*)((char*)ea + grow * 256 + ((j ^ gl15) << 4) + (sub << 3)) = h;
            }
            // zero-pad cols 112..127: granules 14,15 (one uint4 per lane)
            *(uint4*)((char*)ea + grow * 256 + (((14 + sub) ^ gl15) << 4)) =
                make_uint4(0u, 0u, 0u, 0u);
        }
        // ---- issue next-tile prefetch NOW; it flies under MFMA + reduce below
        {
            unsigned long long pkN2 = 0ull;
            if (tile + 2 * G < NTILE)
                pkN2 = srt[(size_t)(tile + 2 * G) * TILE + grow];
            if (tile + G < NTILE)
                gather_issue(x, ef, pkNext, sub, v);
            pkCur = pkNext;
            pkNext = pkN2;
        }
        __builtin_amdgcn_sched_barrier(0);  // don't let the scheduler sink the loads

        __builtin_amdgcn_s_setprio(1);
        // ---- L1 from LDS weights (frags registered before stores; same-wave DS in order)
        {
            short8 bf[2][4];
#pragma unroll
            for (int gi = 0; gi < 2; ++gi)
#pragma unroll
                for (int s = 0; s < 4; ++s)
                    bf[gi][s] = *frag_ptr(ea, (wave * 2 + gi) * 16 + l15, s, l15, q);
#pragma unroll
            for (int mt = 0; mt < 8; ++mt) {
                floatx4 a0 = (floatx4){0.f, 0.f, 0.f, 0.f};
                floatx4 a1 = (floatx4){0.f, 0.f, 0.f, 0.f};
#pragma unroll
                for (int s = 0; s < 4; ++s) {
                    short8 a = *frag_ptr(lw1, mt * 16 + l15, s, l15, q);
                    a0 = __builtin_amdgcn_mfma_f32_16x16x32_bf16(a, bf[0][s], a0, 0, 0, 0);
                    a1 = __builtin_amdgcn_mfma_f32_16x16x32_bf16(a, bf[1][s], a1, 0, 0, 0);
                }
                int f0 = mt * 16 + q * 4;
                const float4 bv = *(const float4*)(lb1 + f0);
                uint2 h0 = make_uint2(pk2(fmaxf(a0[0] + bv.x, 0.f), fmaxf(a0[1] + bv.y, 0.f)),
                                      pk2(fmaxf(a0[2] + bv.z, 0.f), fmaxf(a0[3] + bv.w, 0.f)));
                uint2 h1 = make_uint2(pk2(fmaxf(a1[0] + bv.x, 0.f), fmaxf(a1[1] + bv.y, 0.f)),
                                      pk2(fmaxf(a1[2] + bv.z, 0.f), fmaxf(a1[3] + bv.w, 0.f)));
                int gran = 2 * mt + (q >> 1), off8 = (q & 1) << 3;
                *(uint2*)((char*)ea + (wave * 32 + l15) * 256 + ((gran ^ l15) << 4) + off8) = h0;
                *(uint2*)((char*)ea + (wave * 32 + 16 + l15) * 256 + ((gran ^ l15) << 4) + off8) = h1;
            }
        }
        // ---- L2 from REGISTER weights: only 8 bf reads from LDS per wave
        {
            short8 bf[2][4];
#pragma unroll
            for (int gi = 0; gi < 2; ++gi)
#pragma unroll
                for (int s = 0; s < 4; ++s)
                    bf[gi][s] = *frag_ptr(ea, (wave * 2 + gi) * 16 + l15, s, l15, q);
#pragma unroll
            for (int mt = 0; mt < 8; ++mt) {
                floatx4 a0 = (floatx4){0.f, 0.f, 0.f, 0.f};
                floatx4 a1 = (floatx4){0.f, 0.f, 0.f, 0.f};
#pragma unroll
                for (int s = 0; s < 4; ++s) {
                    a0 = __builtin_amdgcn_mfma_f32_16x16x32_bf16(w2r[mt][s], bf[0][s], a0, 0, 0, 0);
                    a1 = __builtin_amdgcn_mfma_f32_16x16x32_bf16(w2r[mt][s], bf[1][s], a1, 0, 0, 0);
                }
                int f0 = mt * 16 + q * 4;
                const float4 bv = *(const float4*)(lb2 + f0);
                uint2 h0 = make_uint2(pk2(fmaxf(a0[0] + bv.x, 0.f), fmaxf(a0[1] + bv.y, 0.f)),
                                      pk2(fmaxf(a0[2] + bv.z, 0.f), fmaxf(a0[3] + bv.w, 0.f)));
                uint2 h1 = make_uint2(pk2(fmaxf(a1[0] + bv.x, 0.f), fmaxf(a1[1] + bv.y, 0.f)),
                                      pk2(fmaxf(a1[2] + bv.z, 0.f), fmaxf(a1[3] + bv.w, 0.f)));
                int gran = 2 * mt + (q >> 1), off8 = (q & 1) << 3;
                *(uint2*)((char*)ea + (wave * 32 + l15) * 256 + ((gran ^ l15) << 4) + off8) = h0;
                *(uint2*)((char*)ea + (wave * 32 + 16 + l15) * 256 + ((gran ^ l15) << 4) + off8) = h1;
            }
        }
        // ---- L3: msg fp32 in-place (h2 dead after frag reads); b3 added in finalize
        {
            short8 bf[2][4];
#pragma unroll
            for (int gi = 0; gi < 2; ++gi)
#pragma unroll
                for (int s = 0; s < 4; ++s)
                    bf[gi][s] = *frag_ptr(ea, (wave * 2 + gi) * 16 + l15, s, l15, q);
#pragma unroll
            for (int mt = 0; mt < 3; ++mt) {
                floatx4 a0 = (floatx4){0.f, 0.f, 0.f, 0.f};
                floatx4 a1 = (floatx4){0.f, 0.f, 0.f, 0.f};
#pragma unroll
                for (int s = 0; s < 4; ++s) {
                    short8 a = *frag_ptr(lw3, mt * 16 + l15, s, l15, q);
                    a0 = __builtin_amdgcn_mfma_f32_16x16x32_bf16(a, bf[0][s], a0, 0, 0, 0);
                    a1 = __builtin_amdgcn_mfma_f32_16x16x32_bf16(a, bf[1][s], a1, 0, 0, 0);
                }
                int gran = mt * 4 + q;  // fp32 granule, full 16B
                *(float4*)((char*)ea + (wave * 32 + l15) * 256 + ((gran ^ l15) << 4)) =
                    *(float4*)&a0;
                *(float4*)((char*)ea + (wave * 32 + 16 + l15) * 256 + ((gran ^ l15) << 4)) =
                    *(float4*)&a1;
            }
        }
        __builtin_amdgcn_s_setprio(0);
        bar_lgkm();  // A: msg + ltgt visible across waves (vmcnt prefetch stays in flight)
        // ---- wave 0: enumerate target runs (4 chunks of 64)
        if (wave == 0) {
            int base = 0;
#pragma unroll
            for (int c = 0; c < 4; ++c) {
                int p = c * 64 + ln;
                int t = ltgt[p];
                int flag = (p == 0) || (t != ltgt[p - 1]);
                unsigned long long mask = __ballot(flag);
                int sid = base + __popcll(mask & ((1ull << ln) - 1ull));
                if (flag) { seg_start[sid] = p; seg_tgt[sid] = t; }
                base += __popcll(mask);
            }
            if (ln == 0) { nseg = base; seg_start[base] = TILE; }
        }
        bar_lgkm();  // B: segs visible
        // ---- segment reduce; interior segments are tile-exclusive -> plain store
        if (ln < 48) {
            const int gcol = ln >> 2, coff = (ln & 3) << 2;
            const int ns = nseg;
            for (int s = wave; s < ns; s += 8) {
                int a = seg_start[s], bnd = seg_start[s + 1];
                float s0 = 0.f, s1f = 0.f;
                int p = a;
                for (; p + 1 < bnd; p += 2) {
                    s0  += *(const float*)((const char*)ea + p * 256 +
                                           ((gcol ^ (p & 15)) << 4) + coff);
                    s1f += *(const float*)((const char*)ea + (p + 1) * 256 +
                                           ((gcol ^ ((p + 1) & 15)) << 4) + coff);
                }
                if (p < bnd)
                    s0 += *(const float*)((const char*)ea + p * 256 +
                                          ((gcol ^ (p & 15)) << 4) + coff);
                float sum = s0 + s1f;
                float* dst = out_acc + 48 * (size_t)seg_tgt[s] + ln;
                if (s == 0 || s == ns - 1) atomicAdd(dst, sum);  // may span tile boundary
                else *dst = sum;                                 // exclusive run: full sum
            }
        }
        bar_lgkm();  // C: reduce done before next tile overwrites ea/ltgt/segs
    }
}

__global__ void finalize_kernel(const float* __restrict__ x, const int* __restrict__ cnt,
                                const float* __restrict__ b3, float* __restrict__ out) {
    int i = blockIdx.x * 256 + threadIdx.x;  // over NN*12 float4s
    if (i >= NN * 12) return;
    int node = i / 12, j = i % 12;
    float c = (float)cnt[node];
    float4 xv = ((const float4*)x)[i];
    float4 ov = ((const float4*)out)[i];
    float4 bv = ((const float4*)b3)[j];
    float4 r;
    if (c > 0.f) {
        float rc = 1.f / c;
        r.x = xv.x + ov.x * rc + bv.x;
        r.y = xv.y + ov.y * rc + bv.y;
        r.z = xv.z + ov.z * rc + bv.z;
        r.w = xv.w + ov.w * rc + bv.w;
    } else {
        r = xv;
    }
    ((float4*)out)[i] = r;
}

extern "C" void kernel_launch(void* const* d_in, const int* in_sizes, int n_in,
                              void* d_out, int out_size, void* d_ws, size_t ws_size,
                              hipStream_t stream) {
    const float* x  = (const float*)d_in[0];
    const int*   ei = (const int*)d_in[1];
    const float* ef = (const float*)d_in[2];
    const float* W1 = (const float*)d_in[3];
    const float* b1 = (const float*)d_in[4];
    const float* W2 = (const float*)d_in[5];
    const float* b2 = (const float*)d_in[6];
    const float* W3 = (const float*)d_in[7];
    const float* b3 = (const float*)d_in[8];
    float* out = (float*)d_out;

    char* ws = (char*)d_ws;
    int* cnt     = (int*)ws;                    // 400000 B
    int* counter = (int*)(ws + 400000);         // 4 B (zeroed together with cnt)
    int* off     = (int*)(ws + 409600);         // 400000 B
    unsigned short* wt1 = (unsigned short*)(ws + 819456);
    unsigned short* wt2 = wt1 + 16384;
    unsigned short* wt3 = wt2 + 16384;          // ends ~897 KB
    unsigned long long* srt = (unsigned long long*)(ws + 901120);  // 12.8 MB

    hipMemsetAsync(out, 0, (size_t)out_size * sizeof(float), stream);
    hipMemsetAsync(cnt, 0, (size_t)NN * sizeof(int) + 4, stream);
    hist_prep_kernel<<<NTILE + 152, 256, 0, stream>>>(ei, cnt, W1, W2, W3, wt1, wt2, wt3);
    scan_kernel<<<391, 256, 0, stream>>>(cnt, off, counter);
    place_kernel<<<6250, 256, 0, stream>>>(ei, off, srt);
    gemm_kernel<<<256, 512, 0, stream>>>(x, ef, srt, wt1, wt2, wt3, b1, b2, out);
    finalize_kernel<<<4688, 256, 0, stream>>>(x, cnt, b3, out);
}

// Round 3
// 521.651 us; speedup vs baseline: 1.4617x; 1.4617x over previous
//
#include <hip/hip_runtime.h>
#include <hip/hip_bf16.h>

// GNN message passing: gather(x[src],x[tgt],ef) -> MLP(112->128->128->48) -> scatter-mean.
// R11 = R9 (R10's L2-in-registers REVERTED: compiler spilled it -- VGPR stuck at 128,
// FETCH +233MB of scratch re-reads, 1.85x regression) + BARRIER-FREE tile loop.
// Key observation: the MFMA phases only ever touch the wave's own 32 ea rows; the only
// cross-wave traffic was the segment reduce. Making the reduce wave-private (each wave
// enumerates target-runs within its own 32 sorted rows via shfl+ballot, reduces its own
// msg rows, atomicAdd for the 2 chunk-boundary runs / plain store for interior runs --
// sorted srt makes interior runs globally exclusive) removes ALL 3 in-loop barriers.
// Waves fully decouple: gather latency + reduce of one wave hide under MFMA of others;
// setprio(1) around MFMA now arbitrates a real role-split.
// R9 kept: software-pipelined gather (srt 2 ahead, 14xfloat4 1 ahead in regs),
// sched_barrier(0) pinning load issue above the MFMA cluster, weights in LDS.
// R7/R10 lesson: do NOT hoist weight matrices to registers -- spill cliff.

#define NN 100000
#define NE 1600000
#define NF 48
#define TOT 112
#define HID 128
#define TILE 256
#define NTILE 6250  // NE/256

typedef __attribute__((ext_vector_type(8))) short short8;
typedef __attribute__((ext_vector_type(4))) float floatx4;

__device__ __forceinline__ unsigned short f2bf(float f) {
    union { float f; unsigned u; } v; v.f = f;
    unsigned u = v.u;
    return (unsigned short)((u + 0x7FFFu + ((u >> 16) & 1u)) >> 16);  // RNE
}
__device__ __forceinline__ unsigned pk2(float a, float b) {
    __hip_bfloat162 h = __float22bfloat162_rn(make_float2(a, b));
    return *(unsigned*)&h;  // low16 = a, high16 = b
}

// ---- hist (blocks 0..6249) + prep W->WT bf16 (blocks 6250..6401)
__global__ void hist_prep_kernel(const int* __restrict__ ei, int* __restrict__ cnt,
                                 const float* __restrict__ W1, const float* __restrict__ W2,
                                 const float* __restrict__ W3,
                                 unsigned short* __restrict__ wt1,
                                 unsigned short* __restrict__ wt2,
                                 unsigned short* __restrict__ wt3) {
    if (blockIdx.x < NTILE) {
        int e = blockIdx.x * 256 + threadIdx.x;  // NE exact
        atomicAdd(cnt + ei[NE + e], 1);
        return;
    }
    int idx = (blockIdx.x - NTILE) * 256 + threadIdx.x;
    if (idx < 16384) {
        int n = idx >> 7, k = idx & 127;
        wt1[idx] = (k < TOT) ? f2bf(W1[k * HID + n]) : (unsigned short)0;
    } else if (idx < 32768) {
        int j = idx - 16384; int n = j >> 7, k = j & 127;
        wt2[j] = f2bf(W2[k * HID + n]);
    } else if (idx < 38912) {
        int j = idx - 32768; int n = j >> 7, k = j & 127;
        wt3[j] = f2bf(W3[k * NF + n]);
    }
}

// pure block scan + one atomic/block -> exclusive offsets
__global__ void scan_kernel(const int* __restrict__ cnt, int* __restrict__ off,
                            int* __restrict__ counter) {
    __shared__ int sd[256];
    __shared__ int sbase;
    int tid = threadIdx.x;
    int n = blockIdx.x * 256 + tid;
    int v = (n < NN) ? cnt[n] : 0;
    sd[tid] = v;
    __syncthreads();
#pragma unroll
    for (int d = 1; d < 256; d <<= 1) {
        int t = (tid >= d) ? sd[tid - d] : 0;
        __syncthreads();
        sd[tid] += t;
        __syncthreads();
    }
    if (tid == 255) sbase = atomicAdd(counter, sd[255]);
    __syncthreads();
    if (n < NN) off[n] = sbase + sd[tid] - v;  // exclusive
}

__global__ void place_kernel(const int* __restrict__ ei, int* __restrict__ off,
                             unsigned long long* __restrict__ srt) {
    int e = blockIdx.x * 256 + threadIdx.x;  // NE exact
    int t = ei[NE + e];
    int p = atomicAdd(off + t, 1);  // off consumed (dead after this kernel)
    srt[p] = (unsigned long long)e | ((unsigned long long)ei[e] << 21) |
             ((unsigned long long)t << 38);
}

// swizzled LDS frag helper: row stride 256B, 16B granules, granule g stored at g^(row&15)
__device__ __forceinline__ const short8* frag_ptr(const unsigned short* base, int row, int s,
                                                  int lane15, int quad) {
    return (const short8*)((const char*)base + row * 256 + (((s * 4 + quad) ^ lane15) << 4));
}

// issue 14 float4 gather loads for half an edge row (sub = which half)
__device__ __forceinline__ void gather_issue(const float* __restrict__ x,
                                             const float* __restrict__ ef,
                                             unsigned long long pk, int sub, float4* v) {
    int eid = (int)(pk & 0x1FFFFFull);
    int src = (int)((pk >> 21) & 0x1FFFFull);
    int tgt = (int)(pk >> 38);
#pragma unroll
    for (int j = 0; j < 14; ++j) {
        int p = 2 * j + sub;
        const float4* gp;
        if (p < 12)      gp = (const float4*)(x + 48 * (size_t)src) + p;
        else if (p < 24) gp = (const float4*)(x + 48 * (size_t)tgt) + (p - 12);
        else             gp = (const float4*)(ef + 16 * (size_t)eid) + (p - 24);
        v[j] = *gp;
    }
}

__launch_bounds__(512, 2)
__global__ void gemm_kernel(const float* __restrict__ x, const float* __restrict__ ef,
                            const unsigned long long* __restrict__ srt,
                            const unsigned short* __restrict__ wt1,
                            const unsigned short* __restrict__ wt2,
                            const unsigned short* __restrict__ wt3,
                            const float* __restrict__ b1, const float* __restrict__ b2,
                            float* __restrict__ out_acc) {
    __shared__ __align__(16) unsigned short lw1[128 * 128];  // 32 KB
    __shared__ __align__(16) unsigned short lw2[128 * 128];  // 32 KB
    __shared__ __align__(16) unsigned short lw3[48 * 128];   // 12 KB
    __shared__ __align__(16) unsigned short ea[TILE * 128];  // 64 KB: E -> h1 -> h2 -> msg
    __shared__ float lb1[128], lb2[128];
    __shared__ int wseg_start[8][33];  // per-wave run starts + sentinel
    __shared__ int wseg_tgt[8][32];

    const int tid = threadIdx.x;
    // ---- stage weights swizzled (once per persistent block)
    const uint4* s1 = (const uint4*)wt1;
    for (int i = tid; i < 2048; i += 512) {
        int n = i >> 4, g = i & 15;
        *(uint4*)((char*)lw1 + n * 256 + ((g ^ (n & 15)) << 4)) = s1[i];
    }
    const uint4* s2 = (const uint4*)wt2;
    for (int i = tid; i < 2048; i += 512) {
        int n = i >> 4, g = i & 15;
        *(uint4*)((char*)lw2 + n * 256 + ((g ^ (n & 15)) << 4)) = s2[i];
    }
    const uint4* s3 = (const uint4*)wt3;
    for (int i = tid; i < 768; i += 512) {
        int n = i >> 4, g = i & 15;
        *(uint4*)((char*)lw3 + n * 256 + ((g ^ (n & 15)) << 4)) = s3[i];
    }
    if (tid < 128) lb1[tid] = b1[tid];
    else if (tid < 256) lb2[tid - 128] = b2[tid - 128];
    __syncthreads();  // weights read-only from here on; no further barriers needed

    const int l15 = tid & 15;
    const int q = (tid & 63) >> 4;
    const int ln = tid & 63;
    const int wave = tid >> 6;
    const int sub = ln & 1;                  // 2 lanes per edge row
    const int grow = wave * 32 + (ln >> 1);  // tile-local edge row (0..255)
    const int gl15 = grow & 15;
    const int G = gridDim.x;

    // ---- pipeline prologue: srt 2 ahead, gather data 1 ahead (held in registers)
    unsigned long long pkCur = srt[(size_t)blockIdx.x * TILE + grow];
    unsigned long long pkNext = (blockIdx.x + G < NTILE)
        ? srt[(size_t)(blockIdx.x + G) * TILE + grow] : 0ull;
    float4 v[14];
    gather_issue(x, ef, pkCur, sub, v);

    for (int tile = blockIdx.x; tile < NTILE; tile += G) {
        // ---- consume prefetched gather: convert + swizzled store into ea (own rows
        //      only) + per-wave run enumeration (no cross-wave data anywhere)
        int nrun;
        {
            int tgt = (int)(pkCur >> 38);
            int tprev = __shfl(tgt, ln - 2);          // tgt of previous edge row
            int r = ln >> 1;                          // chunk-local row (0..31)
            int startf = (r == 0) || (tgt != tprev);
            unsigned long long mask = __ballot(startf && (sub == 0));
            nrun = __popcll(mask);
            if (startf && sub == 0) {
                int sid = __popcll(mask & ((1ull << ln) - 1ull));
                wseg_start[wave][sid] = r;
                wseg_tgt[wave][sid] = tgt;
            }
            if (ln == 0) wseg_start[wave][nrun] = 32;  // sentinel
#pragma unroll
            for (int j = 0; j < 14; ++j) {
                uint2 h = make_uint2(pk2(v[j].x, v[j].y), pk2(v[j].z, v[j].w));
                *(uint2*)((char*)ea + grow * 256 + ((j ^ gl15) << 4) + (sub << 3)) = h;
            }
            // zero-pad cols 112..127: granules 14,15 (one uint4 per lane)
            *(uint4*)((char*)ea + grow * 256 + (((14 + sub) ^ gl15) << 4)) =
                make_uint4(0u, 0u, 0u, 0u);
        }
        // ---- issue next-tile prefetch NOW; it flies under MFMA + reduce below
        {
            unsigned long long pkN2 = 0ull;
            if (tile + 2 * G < NTILE)
                pkN2 = srt[(size_t)(tile + 2 * G) * TILE + grow];
            if (tile + G < NTILE)
                gather_issue(x, ef, pkNext, sub, v);
            pkCur = pkNext;
            pkNext = pkN2;
        }
        __builtin_amdgcn_sched_barrier(0);  // don't let the scheduler sink the loads

        __builtin_amdgcn_s_setprio(1);
        // ---- L1, L2 in-place (frags registered before stores; same-wave DS in order)
#pragma unroll
        for (int layer = 0; layer < 2; ++layer) {
            const unsigned short* lw = layer ? lw2 : lw1;
            const float* lb = layer ? lb2 : lb1;
            short8 bf[2][4];
#pragma unroll
            for (int gi = 0; gi < 2; ++gi)
#pragma unroll
                for (int s = 0; s < 4; ++s)
                    bf[gi][s] = *frag_ptr(ea, (wave * 2 + gi) * 16 + l15, s, l15, q);
#pragma unroll
            for (int mt = 0; mt < 8; ++mt) {
                floatx4 a0 = (floatx4){0.f, 0.f, 0.f, 0.f};
                floatx4 a1 = (floatx4){0.f, 0.f, 0.f, 0.f};
#pragma unroll
                for (int s = 0; s < 4; ++s) {
                    short8 a = *frag_ptr(lw, mt * 16 + l15, s, l15, q);
                    a0 = __builtin_amdgcn_mfma_f32_16x16x32_bf16(a, bf[0][s], a0, 0, 0, 0);
                    a1 = __builtin_amdgcn_mfma_f32_16x16x32_bf16(a, bf[1][s], a1, 0, 0, 0);
                }
                int f0 = mt * 16 + q * 4;
                const float4 bv = *(const float4*)(lb + f0);
                uint2 h0 = make_uint2(pk2(fmaxf(a0[0] + bv.x, 0.f), fmaxf(a0[1] + bv.y, 0.f)),
                                      pk2(fmaxf(a0[2] + bv.z, 0.f), fmaxf(a0[3] + bv.w, 0.f)));
                uint2 h1 = make_uint2(pk2(fmaxf(a1[0] + bv.x, 0.f), fmaxf(a1[1] + bv.y, 0.f)),
                                      pk2(fmaxf(a1[2] + bv.z, 0.f), fmaxf(a1[3] + bv.w, 0.f)));
                int gran = 2 * mt + (q >> 1), off8 = (q & 1) << 3;
                *(uint2*)((char*)ea + (wave * 32 + l15) * 256 + ((gran ^ l15) << 4) + off8) = h0;
                *(uint2*)((char*)ea + (wave * 32 + 16 + l15) * 256 + ((gran ^ l15) << 4) + off8) = h1;
            }
        }
        // ---- L3: msg fp32 in-place (h2 dead after frag reads)
        {
            short8 bf[2][4];
#pragma unroll
            for (int gi = 0; gi < 2; ++gi)
#pragma unroll
                for (int s = 0; s < 4; ++s)
                    bf[gi][s] = *frag_ptr(ea, (wave * 2 + gi) * 16 + l15, s, l15, q);
#pragma unroll
            for (int mt = 0; mt < 3; ++mt) {
                floatx4 a0 = (floatx4){0.f, 0.f, 0.f, 0.f};
                floatx4 a1 = (floatx4){0.f, 0.f, 0.f, 0.f};
#pragma unroll
                for (int s = 0; s < 4; ++s) {
                    short8 a = *frag_ptr(lw3, mt * 16 + l15, s, l15, q);
                    a0 = __builtin_amdgcn_mfma_f32_16x16x32_bf16(a, bf[0][s], a0, 0, 0, 0);
                    a1 = __builtin_amdgcn_mfma_f32_16x16x32_bf16(a, bf[1][s], a1, 0, 0, 0);
                }
                int gran = mt * 4 + q;  // fp32 granule, full 16B
                *(float4*)((char*)ea + (wave * 32 + l15) * 256 + ((gran ^ l15) << 4)) =
                    *(float4*)&a0;
                *(float4*)((char*)ea + (wave * 32 + 16 + l15) * 256 + ((gran ^ l15) << 4)) =
                    *(float4*)&a1;
            }
        }
        __builtin_amdgcn_s_setprio(0);
        // ---- per-wave segment reduce over OWN 32 rows (no barrier: same-wave DS
        //      ordering covers msg writes above and wseg writes at convert).
        //      Boundary runs (k==0 / k==nrun-1) may continue in neighboring chunks or
        //      blocks -> atomicAdd; interior runs are globally exclusive (sorted srt)
        //      -> plain store. out_acc is zero-initialized.
        if (ln < 48) {
            const int gcol = ln >> 2, coff = (ln & 3) << 2;
            const char* wbase = (const char*)ea + wave * 32 * 256;  // wave*32 % 16 == 0
            for (int k = 0; k < nrun; ++k) {
                int a = wseg_start[wave][k], bnd = wseg_start[wave][k + 1];
                float s0 = 0.f, s1f = 0.f;
                int p = a;
                for (; p + 1 < bnd; p += 2) {
                    s0  += *(const float*)(wbase + p * 256 + ((gcol ^ (p & 15)) << 4) + coff);
                    s1f += *(const float*)(wbase + (p + 1) * 256 +
                                           ((gcol ^ ((p + 1) & 15)) << 4) + coff);
                }
                if (p < bnd)
                    s0 += *(const float*)(wbase + p * 256 + ((gcol ^ (p & 15)) << 4) + coff);
                float sum = s0 + s1f;
                float* dst = out_acc + 48 * (size_t)wseg_tgt[wave][k] + ln;
                if (k == 0 || k == nrun - 1) atomicAdd(dst, sum);  // may span chunk edge
                else *dst = sum;                                   // exclusive run
            }
        }
        // no barrier: each wave proceeds to its next tile independently
    }
}

__global__ void finalize_kernel(const float* __restrict__ x, const int* __restrict__ cnt,
                                const float* __restrict__ b3, float* __restrict__ out) {
    int i = blockIdx.x * 256 + threadIdx.x;  // over NN*12 float4s
    if (i >= NN * 12) return;
    int node = i / 12, j = i % 12;
    float c = (float)cnt[node];
    float4 xv = ((const float4*)x)[i];
    float4 ov = ((const float4*)out)[i];
    float4 bv = ((const float4*)b3)[j];
    float4 r;
    if (c > 0.f) {
        float rc = 1.f / c;
        r.x = xv.x + ov.x * rc + bv.x;
        r.y = xv.y + ov.y * rc + bv.y;
        r.z = xv.z + ov.z * rc + bv.z;
        r.w = xv.w + ov.w * rc + bv.w;
    } else {
        r = xv;
    }
    ((float4*)out)[i] = r;
}

extern "C" void kernel_launch(void* const* d_in, const int* in_sizes, int n_in,
                              void* d_out, int out_size, void* d_ws, size_t ws_size,
                              hipStream_t stream) {
    const float* x  = (const float*)d_in[0];
    const int*   ei = (const int*)d_in[1];
    const float* ef = (const float*)d_in[2];
    const float* W1 = (const float*)d_in[3];
    const float* b1 = (const float*)d_in[4];
    const float* W2 = (const float*)d_in[5];
    const float* b2 = (const float*)d_in[6];
    const float* W3 = (const float*)d_in[7];
    const float* b3 = (const float*)d_in[8];
    float* out = (float*)d_out;

    char* ws = (char*)d_ws;
    int* cnt     = (int*)ws;                    // 400000 B
    int* counter = (int*)(ws + 400000);         // 4 B (zeroed together with cnt)
    int* off     = (int*)(ws + 409600);         // 400000 B
    unsigned short* wt1 = (unsigned short*)(ws + 819456);
    unsigned short* wt2 = wt1 + 16384;
    unsigned short* wt3 = wt2 + 16384;          // ends ~897 KB
    unsigned long long* srt = (unsigned long long*)(ws + 901120);  // 12.8 MB

    hipMemsetAsync(out, 0, (size_t)out_size * sizeof(float), stream);
    hipMemsetAsync(cnt, 0, (size_t)NN * sizeof(int) + 4, stream);
    hist_prep_kernel<<<NTILE + 152, 256, 0, stream>>>(ei, cnt, W1, W2, W3, wt1, wt2, wt3);
    scan_kernel<<<391, 256, 0, stream>>>(cnt, off, counter);
    place_kernel<<<6250, 256, 0, stream>>>(ei, off, srt);
    gemm_kernel<<<256, 512, 0, stream>>>(x, ef, srt, wt1, wt2, wt3, b1, b2, out);
    finalize_kernel<<<4688, 256, 0, stream>>>(x, cnt, b3, out);
}